// Round 1
// baseline (78036.877 us; speedup 1.0000x reference)
//
#include <hip/hip_runtime.h>

#define T_LEN 8192
#define NIN   40
#define E_DIM 256
#define HID   512
#define G4H   2048

#define SCOPE_AGENT __HIP_MEMORY_SCOPE_AGENT

__device__ __forceinline__ float ldg_dev(const float* p) {
  return __hip_atomic_load(p, __ATOMIC_RELAXED, SCOPE_AGENT);
}
__device__ __forceinline__ unsigned ldg_devu(const unsigned* p) {
  return __hip_atomic_load(p, __ATOMIC_RELAXED, SCOPE_AGENT);
}
__device__ __forceinline__ void stg_dev(float* p, float v) {
  __hip_atomic_store(p, v, __ATOMIC_RELAXED, SCOPE_AGENT);
}
__device__ __forceinline__ void stg_devu(unsigned* p, unsigned v) {
  __hip_atomic_store(p, v, __ATOMIC_RELAXED, SCOPE_AGENT);
}

__device__ __forceinline__ float sigm(float x) {
  x = fminf(20.f, fmaxf(-20.f, x));
  float e = __builtin_amdgcn_exp2f(-1.442695040888963f * x);
  return __builtin_amdgcn_rcpf(1.f + e);
}
__device__ __forceinline__ float tanh_f(float x) {
  x = fminf(10.f, fmaxf(-10.f, x));
  float e = __builtin_amdgcn_exp2f(-2.885390081777927f * x);  // e^(-2x)
  return (1.f - e) * __builtin_amdgcn_rcpf(1.f + e);
}

// ---------------- phase 0: W_comb = W_ih0 @ W_in  [2048 x 40], bias_comb ----
__global__ __launch_bounds__(64) void prep_kernel(
    const float* __restrict__ W_in, const float* __restrict__ b_in,
    const float* __restrict__ W_ih0, const float* __restrict__ b_ih0,
    const float* __restrict__ b_hh0,
    float* __restrict__ W_comb, float* __restrict__ bias_comb)
{
  const int r = blockIdx.x;        // 0..2047
  const int lane = threadIdx.x;    // 0..63
  float bp = 0.f;
  for (int e = lane; e < E_DIM; e += 64) bp += W_ih0[(size_t)r * E_DIM + e] * b_in[e];
  float acc = 0.f;
  if (lane < NIN) {
    for (int e = 0; e < E_DIM; ++e)
      acc += W_ih0[(size_t)r * E_DIM + e] * W_in[(size_t)e * NIN + lane];
  }
#pragma unroll
  for (int m = 1; m < 64; m <<= 1) bp += __shfl_xor(bp, m, 64);
  if (lane < NIN) W_comb[(size_t)r * NIN + lane] = acc;
  if (lane == 0) bias_comb[r] = bp + b_ih0[r] + b_hh0[r];
}

// ---------------- phase 1: pipelined 2-layer persistent scan ----------------
// grid = 48 blocks x 1024 threads. blocks 0..15: layer0 (32 units each).
// blocks 16..47: layer1 (16 units each). Cross-wg exchange via device-scope
// (sc0 sc1) loads/stores through the MALL + per-(step,wg) tag words.
__global__ __launch_bounds__(1024, 4) void scan_kernel(
    const float* __restrict__ in_states,
    const float* __restrict__ W_hh0,
    const float* __restrict__ W_ih1,
    const float* __restrict__ W_hh1,
    const float* __restrict__ b_ih1,
    const float* __restrict__ b_hh1,
    const float* __restrict__ W_comb,
    const float* __restrict__ bias_comb,
    float* __restrict__ h1buf, float* __restrict__ h2buf,
    unsigned* __restrict__ flags0, unsigned* __restrict__ flags1,
    float* __restrict__ d_out)
{
  const int tid  = threadIdx.x;
  const int wid  = tid >> 6;
  const int lane = tid & 63;
  const int bid  = blockIdx.x;

  __shared__ float lds_wcomb[128 * (NIN + 1)];
  __shared__ float lds_in[NIN];
  __shared__ float lds_indot[128];

  if (bid < 16) {
    // ======================= layer 0 =======================
    const int u0 = bid * 32;
    // stage W_comb slice into LDS (padded stride NIN+1=41 -> conflict-free)
    for (int i = tid; i < 128 * NIN; i += 1024) {
      int lr = i / NIN, k = i - lr * NIN;
      int R = (lr & 3) * HID + u0 + (lr >> 2);          // lr = ul*4 + g
      lds_wcomb[lr * (NIN + 1) + k] = W_comb[(size_t)R * NIN + k];
    }
    // W_hh0 slice into registers: wave wid rows lr=wid*8+q, lane cols [lane*8, +8)
    float w[8][8];
#pragma unroll
    for (int q = 0; q < 8; ++q) {
      int R = (q & 3) * HID + u0 + wid * 2 + (q >> 2);
      const float4* p = (const float4*)(W_hh0 + (size_t)R * HID + lane * 8);
      float4 a = p[0], b = p[1];
      w[q][0]=a.x; w[q][1]=a.y; w[q][2]=a.z; w[q][3]=a.w;
      w[q][4]=b.x; w[q][5]=b.y; w[q][6]=b.z; w[q][7]=b.w;
    }
    float my_bias = 0.f;
    if (tid < 128) {
      int R = (tid & 3) * HID + u0 + (tid >> 2);
      my_bias = bias_comb[R];
    }
    if (tid < NIN) lds_in[tid] = in_states[tid];
    __syncthreads();
    if (tid < 128) {                 // indot[0]
      float s = my_bias;
#pragma unroll
      for (int k = 0; k < NIN; ++k) s += lds_wcomb[tid * (NIN + 1) + k] * lds_in[k];
      lds_indot[tid] = s;
    }

    float c_reg = 0.f;
    for (int t = 0; t < T_LEN; ++t) {
      if (wid == 0 && lane < 16 && t > 0) {
        const unsigned* fp = flags0 + (size_t)(t - 1) * 16 + lane;
        while (ldg_devu(fp) == 0u) {}
      }
      __syncthreads();  // B1: poll done; lds_indot[t] visible; lds_in free
      float inval = 0.f;
      if (tid < NIN && t + 1 < T_LEN) inval = in_states[(size_t)(t + 1) * NIN + tid];
      float hv[8];
      if (t > 0) {
        const float* hp = h1buf + (size_t)(t - 1) * HID + lane * 8;
#pragma unroll
        for (int j = 0; j < 8; ++j) hv[j] = ldg_dev(hp + j);
      } else {
#pragma unroll
        for (int j = 0; j < 8; ++j) hv[j] = 0.f;
      }
      if (tid < NIN) lds_in[tid] = inval;
      float acc[8] = {0,0,0,0,0,0,0,0};
#pragma unroll
      for (int cc = 0; cc < 8; ++cc) {
#pragma unroll
        for (int q = 0; q < 8; ++q) acc[q] = fmaf(w[q][cc], hv[cc], acc[q]);
      }
#pragma unroll
      for (int m = 1; m < 64; m <<= 1) {
#pragma unroll
        for (int q = 0; q < 8; ++q) acc[q] += __shfl_xor(acc[q], m, 64);
      }
      if (lane < 2) {
        float pre[4];
#pragma unroll
        for (int g = 0; g < 4; ++g) pre[g] = lane ? acc[4 + g] : acc[g];
#pragma unroll
        for (int g = 0; g < 4; ++g) pre[g] += lds_indot[wid * 8 + lane * 4 + g];
        float gi = sigm(pre[0]);
        float gf = sigm(pre[1]);
        float gg = tanh_f(pre[2]);
        float go = sigm(pre[3]);
        c_reg = gf * c_reg + gi * gg;
        float hnew = go * tanh_f(c_reg);
        int u = u0 + wid * 2 + lane;
        stg_dev(h1buf + (size_t)t * HID + u, hnew);
        if (t == T_LEN - 1) {
          d_out[T_LEN + u] = hnew;              // hT0
          d_out[T_LEN + 2 * HID + u] = c_reg;   // cT0
        }
      }
      asm volatile("s_waitcnt vmcnt(0)" ::: "memory");
      __syncthreads();  // B2: all data stores drained; lds_in complete
      if (tid == 0) stg_devu(flags0 + (size_t)t * 16 + bid, 1u);
      if (tid < 128 && t + 1 < T_LEN) {         // indot[t+1] (off critical path)
        float s = my_bias;
#pragma unroll
        for (int k = 0; k < NIN; ++k) s += lds_wcomb[tid * (NIN + 1) + k] * lds_in[k];
        lds_indot[tid] = s;
      }
    }
  } else {
    // ======================= layer 1 =======================
    const int wg = bid - 16;
    const int u0 = wg * 16;
    // [W_ih1 | W_hh1] rows for unit (u0+wid), gates 0..3; lane cols 16 wide
    float w[4][16];
    {
      const float* Wsrc = (lane < 32) ? W_ih1 : W_hh1;
      int colbase = (lane & 31) * 16;
#pragma unroll
      for (int g = 0; g < 4; ++g) {
        int R = g * HID + u0 + wid;
        const float4* p = (const float4*)(Wsrc + (size_t)R * HID + colbase);
        float4 x0 = p[0], x1 = p[1], x2 = p[2], x3 = p[3];
        w[g][0]=x0.x;  w[g][1]=x0.y;  w[g][2]=x0.z;  w[g][3]=x0.w;
        w[g][4]=x1.x;  w[g][5]=x1.y;  w[g][6]=x1.z;  w[g][7]=x1.w;
        w[g][8]=x2.x;  w[g][9]=x2.y;  w[g][10]=x2.z; w[g][11]=x2.w;
        w[g][12]=x3.x; w[g][13]=x3.y; w[g][14]=x3.z; w[g][15]=x3.w;
      }
    }
    float bias[4];
#pragma unroll
    for (int g = 0; g < 4; ++g) {
      int R = g * HID + u0 + wid;
      bias[g] = b_ih1[R] + b_hh1[R];
    }
    float c_reg = 0.f;
    for (int t = 0; t < T_LEN; ++t) {
      if (wid == 0) {
        const unsigned* fp = nullptr;
        if (lane < 16) fp = flags0 + (size_t)t * 16 + lane;                 // h1[t]
        else if (lane < 48 && t > 0) fp = flags1 + (size_t)(t - 1) * 32 + (lane - 16); // h2[t-1]
        if (fp) { while (ldg_devu(fp) == 0u) {} }
      }
      __syncthreads();  // B1
      float hv[16];
      {
        int tprev = (t > 0) ? (t - 1) : 0;
        const float* hp = (lane < 32)
            ? (h1buf + (size_t)t * HID + (lane & 31) * 16)
            : (h2buf + (size_t)tprev * HID + (lane & 31) * 16);
        bool valid = (lane < 32) || (t > 0);
#pragma unroll
        for (int j = 0; j < 16; ++j) {
          float v = ldg_dev(hp + j);
          hv[j] = valid ? v : 0.f;
        }
      }
      float acc[4] = {0,0,0,0};
#pragma unroll
      for (int cc = 0; cc < 16; ++cc) {
#pragma unroll
        for (int g = 0; g < 4; ++g) acc[g] = fmaf(w[g][cc], hv[cc], acc[g]);
      }
#pragma unroll
      for (int m = 1; m < 64; m <<= 1) {
#pragma unroll
        for (int g = 0; g < 4; ++g) acc[g] += __shfl_xor(acc[g], m, 64);
      }
      float gi = sigm(acc[0] + bias[0]);
      float gf = sigm(acc[1] + bias[1]);
      float gg = tanh_f(acc[2] + bias[2]);
      float go = sigm(acc[3] + bias[3]);
      c_reg = gf * c_reg + gi * gg;
      float hnew = go * tanh_f(c_reg);
      if (lane == 0) {
        int u = u0 + wid;
        stg_dev(h2buf + (size_t)t * HID + u, hnew);
        if (t == T_LEN - 1) {
          d_out[T_LEN + HID + u] = hnew;          // hT1
          d_out[T_LEN + 3 * HID + u] = c_reg;     // cT1
        }
      }
      asm volatile("s_waitcnt vmcnt(0)" ::: "memory");
      __syncthreads();  // B2
      if (tid == 0) stg_devu(flags1 + (size_t)t * 32 + wg, 1u);
    }
  }
}

// ---------------- phase 2: outputs[t] = W_out . h2[t] + b_out ----------------
__global__ __launch_bounds__(256) void out_kernel(
    const float* __restrict__ h2buf, const float* __restrict__ W_out,
    const float* __restrict__ b_out, float* __restrict__ d_out)
{
  int t = blockIdx.x * 4 + (threadIdx.x >> 6);
  int lane = threadIdx.x & 63;
  const float4* hp = (const float4*)(h2buf + (size_t)t * HID + lane * 8);
  const float4* wp = (const float4*)(W_out + lane * 8);
  float4 a = hp[0], b = hp[1], wa = wp[0], wb = wp[1];
  float s = a.x*wa.x + a.y*wa.y + a.z*wa.z + a.w*wa.w
          + b.x*wb.x + b.y*wb.y + b.z*wb.z + b.w*wb.w;
#pragma unroll
  for (int m = 1; m < 64; m <<= 1) s += __shfl_xor(s, m, 64);
  if (lane == 0) d_out[t] = s + b_out[0];
}

extern "C" void kernel_launch(void* const* d_in, const int* in_sizes, int n_in,
                              void* d_out, int out_size, void* d_ws, size_t ws_size,
                              hipStream_t stream) {
  const float* in_states = (const float*)d_in[0];
  const float* W_in  = (const float*)d_in[1];
  const float* b_in  = (const float*)d_in[2];
  const float* W_ih0 = (const float*)d_in[3];
  const float* W_hh0 = (const float*)d_in[4];
  const float* b_ih0 = (const float*)d_in[5];
  const float* b_hh0 = (const float*)d_in[6];
  const float* W_ih1 = (const float*)d_in[7];
  const float* W_hh1 = (const float*)d_in[8];
  const float* b_ih1 = (const float*)d_in[9];
  const float* b_hh1 = (const float*)d_in[10];
  const float* W_out = (const float*)d_in[11];
  const float* b_out = (const float*)d_in[12];

  float* ws = (float*)d_ws;
  size_t o = 0;
  float* W_comb = ws + o;    o += (size_t)G4H * NIN;     // 81920
  float* bias_comb = ws + o; o += G4H;                   // 2048
  float* h1buf = ws + o;     o += (size_t)T_LEN * HID;   // 4M floats
  float* h2buf = ws + o;     o += (size_t)T_LEN * HID;   // 4M floats
  unsigned* flags0 = (unsigned*)(ws + o); o += (size_t)T_LEN * 16;
  unsigned* flags1 = (unsigned*)(ws + o); o += (size_t)T_LEN * 32;
  // total ~35.5 MB of d_ws

  // tags must start at 0 (d_ws is re-poisoned to 0xAA before every launch)
  hipMemsetAsync(flags0, 0, (size_t)T_LEN * 48 * sizeof(unsigned), stream);

  prep_kernel<<<G4H, 64, 0, stream>>>(W_in, b_in, W_ih0, b_ih0, b_hh0,
                                      W_comb, bias_comb);
  scan_kernel<<<48, 1024, 0, stream>>>(in_states, W_hh0, W_ih1, W_hh1,
                                       b_ih1, b_hh1, W_comb, bias_comb,
                                       h1buf, h2buf, flags0, flags1,
                                       (float*)d_out);
  out_kernel<<<2048, 256, 0, stream>>>(h2buf, W_out, b_out, (float*)d_out);
}

// Round 2
// 25222.495 us; speedup vs baseline: 3.0939x; 3.0939x over previous
//
#include <hip/hip_runtime.h>

#define T_LEN 8192
#define NIN   40
#define E_DIM 256
#define HID   512
#define G4H   2048

// ---------- explicit cross-XCD (MALL) coherent access, inline asm ----------
__device__ __forceinline__ float4 ld4_sc(const float* p) {
  float4 v;
  asm volatile("global_load_dwordx4 %0, %1, off sc0 sc1" : "=v"(v) : "v"(p));
  return v;  // NOT ready until s_waitcnt vmcnt(0)!
}
__device__ __forceinline__ unsigned ld_flag(const unsigned* p) {
  unsigned v;
  asm volatile("global_load_dword %0, %1, off sc0 sc1\n\ts_waitcnt vmcnt(0)"
               : "=v"(v) : "v"(p) : "memory");
  return v;
}
__device__ __forceinline__ void st_sc(float* p, float v) {
  asm volatile("global_store_dword %0, %1, off sc0 sc1" :: "v"(p), "v"(v) : "memory");
}
__device__ __forceinline__ void st_flag(unsigned* p, unsigned v) {
  asm volatile("global_store_dword %0, %1, off sc0 sc1" :: "v"(p), "v"(v) : "memory");
}
#define VM_FENCE() do { asm volatile("s_waitcnt vmcnt(0)" ::: "memory"); \
                        __builtin_amdgcn_sched_barrier(0); } while (0)

__device__ __forceinline__ float sigm(float x) {
  x = fminf(20.f, fmaxf(-20.f, x));
  float e = __builtin_amdgcn_exp2f(-1.442695040888963f * x);
  return __builtin_amdgcn_rcpf(1.f + e);
}
__device__ __forceinline__ float tanh_f(float x) {
  x = fminf(10.f, fmaxf(-10.f, x));
  float e = __builtin_amdgcn_exp2f(-2.885390081777927f * x);  // e^(-2x)
  return (1.f - e) * __builtin_amdgcn_rcpf(1.f + e);
}
// pick among 4 values by small runtime index (compiles to cndmask chain)
__device__ __forceinline__ float sel4(int k, float a0, float a1, float a2, float a3) {
  float r = a0;
  r = (k == 1) ? a1 : r;
  r = (k == 2) ? a2 : r;
  r = (k == 3) ? a3 : r;
  return r;
}

// ---------------- phase 0: W_comb = W_ih0 @ W_in  [2048 x 40], bias_comb ----
__global__ __launch_bounds__(64) void prep_kernel(
    const float* __restrict__ W_in, const float* __restrict__ b_in,
    const float* __restrict__ W_ih0, const float* __restrict__ b_ih0,
    const float* __restrict__ b_hh0,
    float* __restrict__ W_comb, float* __restrict__ bias_comb)
{
  const int r = blockIdx.x;        // 0..2047
  const int lane = threadIdx.x;    // 0..63
  float bp = 0.f;
  for (int e = lane; e < E_DIM; e += 64) bp += W_ih0[(size_t)r * E_DIM + e] * b_in[e];
  float acc = 0.f;
  if (lane < NIN) {
    for (int e = 0; e < E_DIM; ++e)
      acc += W_ih0[(size_t)r * E_DIM + e] * W_in[(size_t)e * NIN + lane];
  }
#pragma unroll
  for (int m = 1; m < 64; m <<= 1) bp += __shfl_xor(bp, m, 64);
  if (lane < NIN) W_comb[(size_t)r * NIN + lane] = acc;
  if (lane == 0) bias_comb[r] = bp + b_ih0[r] + b_hh0[r];
}

// ---------------- phase 1: pipelined 2-layer persistent scan ----------------
// 48 blocks x 1024 threads. blocks 0..15: layer0 (32 units each).
// blocks 16..47: layer1 (16 units each).
__global__ __launch_bounds__(1024, 4) void scan_kernel(
    const float* __restrict__ in_states,
    const float* __restrict__ W_hh0,
    const float* __restrict__ W_ih1,
    const float* __restrict__ W_hh1,
    const float* __restrict__ b_ih1,
    const float* __restrict__ b_hh1,
    const float* __restrict__ W_comb,
    const float* __restrict__ bias_comb,
    float* __restrict__ h1buf, float* __restrict__ h2buf,
    unsigned* __restrict__ flags0, unsigned* __restrict__ flags1,
    float* __restrict__ d_out)
{
  const int tid  = threadIdx.x;
  const int wid  = tid >> 6;
  const int lane = tid & 63;
  const int bid  = blockIdx.x;

  __shared__ float lds_wcomb[128 * (NIN + 1)];
  __shared__ float lds_in[NIN];
  __shared__ float lds_indot[128];

  if (bid < 16) {
    // ======================= layer 0 =======================
    const int u0 = bid * 32;
    const int uA = u0 + wid * 2;                 // this wave's first unit
    const int G  = (lane & 2) | ((lane >> 2) & 1);   // gate id after collapse
    const int ulocal4 = (wid * 2 + (lane & 1)) * 4;

    // stage W_comb slice into LDS (padded stride 41)
    for (int i = tid; i < 128 * NIN; i += 1024) {
      int lr = i / NIN, k = i - lr * NIN;
      int R = (lr & 3) * HID + u0 + (lr >> 2);   // lr = ul*4 + g
      lds_wcomb[lr * (NIN + 1) + k] = W_comb[(size_t)R * NIN + k];
    }
    // W_hh0 rows q=0..7 (unit uA+(q>>2), gate q&3), lane cols [lane*8, +8)
    float w[8][8];
#pragma unroll
    for (int q = 0; q < 8; ++q) {
      int R = (q & 3) * HID + uA + (q >> 2);
      const float4* p = (const float4*)(W_hh0 + (size_t)R * HID + lane * 8);
      float4 a = p[0], b = p[1];
      w[q][0]=a.x; w[q][1]=a.y; w[q][2]=a.z; w[q][3]=a.w;
      w[q][4]=b.x; w[q][5]=b.y; w[q][6]=b.z; w[q][7]=b.w;
    }
    float my_bias = 0.f;
    if (tid >= 128 && tid < 256) {               // indot workers: rows r=tid-128
      int r = tid - 128;
      my_bias = bias_comb[(size_t)((r & 3) * HID + u0 + (r >> 2))];
    }
    float inreg = 0.f;
    if (tid >= 64 && tid < 64 + NIN) inreg = in_states[NIN + (tid - 64)];  // in[1]
    if (tid < NIN) lds_in[tid] = in_states[tid];                           // in[0]
    __syncthreads();
    if (tid >= 128 && tid < 256) {               // indot[0]
      int r = tid - 128;
      float s = my_bias;
#pragma unroll
      for (int k = 0; k < NIN; ++k) s += lds_wcomb[r * (NIN + 1) + k] * lds_in[k];
      lds_indot[r] = s;
    }

    float c_reg = 0.f;
    for (int t = 0; t < T_LEN; ++t) {
      if (wid == 0 && t > 0 && lane < 16) {
        const unsigned* fp = flags0 + (size_t)(t - 1) * 16 + lane;
        while (ld_flag(fp) == 0u) {}
      }
      __syncthreads();  // B1
      // wave1: publish in[t+1] to LDS, prefetch in[t+2] (off critical path)
      if (tid >= 64 && tid < 64 + NIN) {
        lds_in[tid - 64] = inreg;
        int t2 = (t + 2 < T_LEN) ? (t + 2) : (T_LEN - 1);
        inreg = in_states[(size_t)t2 * NIN + (tid - 64)];
      }
      // h[t-1] load: 2x dwordx4 sc0sc1, ONE drain
      float hv[8];
      if (t > 0) {
        const float* hp = h1buf + (size_t)(t - 1) * HID + lane * 8;
        float4 A = ld4_sc(hp);
        float4 B = ld4_sc(hp + 4);
        VM_FENCE();
        hv[0]=A.x; hv[1]=A.y; hv[2]=A.z; hv[3]=A.w;
        hv[4]=B.x; hv[5]=B.y; hv[6]=B.z; hv[7]=B.w;
      } else {
#pragma unroll
        for (int j = 0; j < 8; ++j) hv[j] = 0.f;
      }
      float acc[8] = {0,0,0,0,0,0,0,0};
#pragma unroll
      for (int cc = 0; cc < 8; ++cc) {
#pragma unroll
        for (int q = 0; q < 8; ++q) acc[q] = fmaf(w[q][cc], hv[cc], acc[q]);
      }
      // collapsing butterfly: 8 accs / 64 lanes -> 1 value per lane (10 shfls)
      float a4[4];
#pragma unroll
      for (int g = 0; g < 4; ++g) {
        float send = (lane & 1) ? acc[g] : acc[g + 4];
        float recv = __shfl_xor(send, 1, 64);
        a4[g] = ((lane & 1) ? acc[g + 4] : acc[g]) + recv;
      }
      float b2[2];
#pragma unroll
      for (int j = 0; j < 2; ++j) {
        float send = (lane & 2) ? a4[j] : a4[j + 2];
        float recv = __shfl_xor(send, 2, 64);
        b2[j] = ((lane & 2) ? a4[j + 2] : a4[j]) + recv;
      }
      float c1;
      {
        float send = (lane & 4) ? b2[0] : b2[1];
        float recv = __shfl_xor(send, 4, 64);
        c1 = ((lane & 4) ? b2[1] : b2[0]) + recv;
      }
      c1 += __shfl_xor(c1, 8, 64);
      c1 += __shfl_xor(c1, 16, 64);
      c1 += __shfl_xor(c1, 32, 64);
      // lane now holds dot for (unit uA+(lane&1), gate G); add input-dot
      float pre = c1 + lds_indot[ulocal4 + G];
      // gather all 4 gates (shfl partners share the unit)
      float s2 = __shfl_xor(pre, 2, 64);   // gate G^2
      float s4 = __shfl_xor(pre, 4, 64);   // gate G^1
      float s6 = __shfl_xor(pre, 6, 64);   // gate G^3
      float prei = sel4(G,     pre, s4, s2, s6);
      float pref = sel4(G ^ 1, pre, s4, s2, s6);
      float preg = sel4(G ^ 2, pre, s4, s2, s6);
      float preo = sel4(G ^ 3, pre, s4, s2, s6);
      float gi = sigm(prei), gf = sigm(pref), gg = tanh_f(preg), go = sigm(preo);
      c_reg = gf * c_reg + gi * gg;
      float hnew = go * tanh_f(c_reg);
      if (lane < 2) {
        st_sc(h1buf + (size_t)t * HID + uA + lane, hnew);
        if (t == T_LEN - 1) {
          d_out[T_LEN + uA + lane] = hnew;              // hT0
          d_out[T_LEN + 2 * HID + uA + lane] = c_reg;   // cT0
        }
      }
      VM_FENCE();
      __syncthreads();  // B2
      if (tid == 0) st_flag(flags0 + (size_t)t * 16 + bid, 1u);
      if (tid >= 128 && tid < 256 && t + 1 < T_LEN) {   // indot[t+1], off path
        int r = tid - 128;
        float s = my_bias;
#pragma unroll
        for (int k = 0; k < NIN; ++k) s += lds_wcomb[r * (NIN + 1) + k] * lds_in[k];
        lds_indot[r] = s;
      }
    }
  } else {
    // ======================= layer 1 =======================
    const int wg = bid - 16;
    const int u0 = wg * 16;
    const int u  = u0 + wid;                      // this wave's unit
    const int G  = ((lane & 1) << 1) | ((lane >> 1) & 1);
    // [W_ih1 | W_hh1] rows gate 0..3 of unit u; lane cols 16 wide
    float w[4][16];
    {
      const float* Wsrc = (lane < 32) ? W_ih1 : W_hh1;
      int colbase = (lane & 31) * 16;
#pragma unroll
      for (int g = 0; g < 4; ++g) {
        int R = g * HID + u;
        const float4* p = (const float4*)(Wsrc + (size_t)R * HID + colbase);
        float4 x0 = p[0], x1 = p[1], x2 = p[2], x3 = p[3];
        w[g][0]=x0.x;  w[g][1]=x0.y;  w[g][2]=x0.z;  w[g][3]=x0.w;
        w[g][4]=x1.x;  w[g][5]=x1.y;  w[g][6]=x1.z;  w[g][7]=x1.w;
        w[g][8]=x2.x;  w[g][9]=x2.y;  w[g][10]=x2.z; w[g][11]=x2.w;
        w[g][12]=x3.x; w[g][13]=x3.y; w[g][14]=x3.z; w[g][15]=x3.w;
      }
    }
    const float bias_lane = b_ih1[G * HID + u] + b_hh1[G * HID + u];
    float c_reg = 0.f;
    for (int t = 0; t < T_LEN; ++t) {
      if (wid == 0) {
        const unsigned* fp = nullptr;
        if (lane < 16) fp = flags0 + (size_t)t * 16 + lane;                       // h1[t]
        else if (lane < 48 && t > 0) fp = flags1 + (size_t)(t - 1) * 32 + (lane - 16); // h2[t-1]
        if (fp) { while (ld_flag(fp) == 0u) {} }
      }
      __syncthreads();  // B1
      float hv[16];
      {
        int col = (lane & 31) * 16;
        int tp = (t > 0) ? (t - 1) : 0;
        const float* hp = (lane < 32) ? (h1buf + (size_t)t * HID + col)
                                      : (h2buf + (size_t)tp * HID + col);
        bool hvalid = (lane < 32) || (t > 0);
        float4 A = ld4_sc(hp);
        float4 B = ld4_sc(hp + 4);
        float4 C = ld4_sc(hp + 8);
        float4 D = ld4_sc(hp + 12);
        VM_FENCE();
        float tmp[16];
        tmp[0]=A.x; tmp[1]=A.y; tmp[2]=A.z; tmp[3]=A.w;
        tmp[4]=B.x; tmp[5]=B.y; tmp[6]=B.z; tmp[7]=B.w;
        tmp[8]=C.x; tmp[9]=C.y; tmp[10]=C.z; tmp[11]=C.w;
        tmp[12]=D.x; tmp[13]=D.y; tmp[14]=D.z; tmp[15]=D.w;
#pragma unroll
        for (int j = 0; j < 16; ++j) hv[j] = hvalid ? tmp[j] : 0.f;
      }
      float acc[4] = {0,0,0,0};
#pragma unroll
      for (int cc = 0; cc < 16; ++cc) {
#pragma unroll
        for (int g = 0; g < 4; ++g) acc[g] = fmaf(w[g][cc], hv[cc], acc[g]);
      }
      // collapsing butterfly: 4 accs -> 1 per lane (7 shfls)
      float b2[2];
#pragma unroll
      for (int j = 0; j < 2; ++j) {
        float send = (lane & 1) ? acc[j] : acc[j + 2];
        float recv = __shfl_xor(send, 1, 64);
        b2[j] = ((lane & 1) ? acc[j + 2] : acc[j]) + recv;
      }
      float c1;
      {
        float send = (lane & 2) ? b2[0] : b2[1];
        float recv = __shfl_xor(send, 2, 64);
        c1 = ((lane & 2) ? b2[1] : b2[0]) + recv;
      }
      c1 += __shfl_xor(c1, 4, 64);
      c1 += __shfl_xor(c1, 8, 64);
      c1 += __shfl_xor(c1, 16, 64);
      c1 += __shfl_xor(c1, 32, 64);
      float pre = c1 + bias_lane;
      float s1 = __shfl_xor(pre, 1, 64);   // gate G^2
      float s2 = __shfl_xor(pre, 2, 64);   // gate G^1
      float s3 = __shfl_xor(pre, 3, 64);   // gate G^3
      float prei = sel4(G,     pre, s2, s1, s3);
      float pref = sel4(G ^ 1, pre, s2, s1, s3);
      float preg = sel4(G ^ 2, pre, s2, s1, s3);
      float preo = sel4(G ^ 3, pre, s2, s1, s3);
      float gi = sigm(prei), gf = sigm(pref), gg = tanh_f(preg), go = sigm(preo);
      c_reg = gf * c_reg + gi * gg;
      float hnew = go * tanh_f(c_reg);
      if (lane == 0) {
        st_sc(h2buf + (size_t)t * HID + u, hnew);
        if (t == T_LEN - 1) {
          d_out[T_LEN + HID + u] = hnew;          // hT1
          d_out[T_LEN + 3 * HID + u] = c_reg;     // cT1
        }
      }
      VM_FENCE();
      __syncthreads();  // B2
      if (tid == 0) st_flag(flags1 + (size_t)t * 32 + wg, 1u);
    }
  }
}

// ---------------- phase 2: outputs[t] = W_out . h2[t] + b_out ----------------
__global__ __launch_bounds__(256) void out_kernel(
    const float* __restrict__ h2buf, const float* __restrict__ W_out,
    const float* __restrict__ b_out, float* __restrict__ d_out)
{
  int t = blockIdx.x * 4 + (threadIdx.x >> 6);
  int lane = threadIdx.x & 63;
  const float4* hp = (const float4*)(h2buf + (size_t)t * HID + lane * 8);
  const float4* wp = (const float4*)(W_out + lane * 8);
  float4 a = hp[0], b = hp[1], wa = wp[0], wb = wp[1];
  float s = a.x*wa.x + a.y*wa.y + a.z*wa.z + a.w*wa.w
          + b.x*wb.x + b.y*wb.y + b.z*wb.z + b.w*wb.w;
#pragma unroll
  for (int m = 1; m < 64; m <<= 1) s += __shfl_xor(s, m, 64);
  if (lane == 0) d_out[t] = s + b_out[0];
}

extern "C" void kernel_launch(void* const* d_in, const int* in_sizes, int n_in,
                              void* d_out, int out_size, void* d_ws, size_t ws_size,
                              hipStream_t stream) {
  const float* in_states = (const float*)d_in[0];
  const float* W_in  = (const float*)d_in[1];
  const float* b_in  = (const float*)d_in[2];
  const float* W_ih0 = (const float*)d_in[3];
  const float* W_hh0 = (const float*)d_in[4];
  const float* b_ih0 = (const float*)d_in[5];
  const float* b_hh0 = (const float*)d_in[6];
  const float* W_ih1 = (const float*)d_in[7];
  const float* W_hh1 = (const float*)d_in[8];
  const float* b_ih1 = (const float*)d_in[9];
  const float* b_hh1 = (const float*)d_in[10];
  const float* W_out = (const float*)d_in[11];
  const float* b_out = (const float*)d_in[12];

  float* ws = (float*)d_ws;
  size_t o = 0;
  float* W_comb = ws + o;    o += (size_t)G4H * NIN;     // 81920
  float* bias_comb = ws + o; o += G4H;                   // 2048
  float* h1buf = ws + o;     o += (size_t)T_LEN * HID;   // 4M floats
  float* h2buf = ws + o;     o += (size_t)T_LEN * HID;   // 4M floats
  unsigned* flags0 = (unsigned*)(ws + o); o += (size_t)T_LEN * 16;
  unsigned* flags1 = (unsigned*)(ws + o); o += (size_t)T_LEN * 32;

  // tags must start at 0 (d_ws is re-poisoned to 0xAA before every launch)
  hipMemsetAsync(flags0, 0, (size_t)T_LEN * 48 * sizeof(unsigned), stream);

  prep_kernel<<<G4H, 64, 0, stream>>>(W_in, b_in, W_ih0, b_ih0, b_hh0,
                                      W_comb, bias_comb);
  scan_kernel<<<48, 1024, 0, stream>>>(in_states, W_hh0, W_ih1, W_hh1,
                                       b_ih1, b_hh1, W_comb, bias_comb,
                                       h1buf, h2buf, flags0, flags1,
                                       (float*)d_out);
  out_kernel<<<2048, 256, 0, stream>>>(h2buf, W_out, b_out, (float*)d_out);
}